// Round 1
// baseline (100.643 us; speedup 1.0000x reference)
//
#include <hip/hip_runtime.h>

#define NUM_CLASSES 1024
#define FEAT_DIM    512
#define BATCH       16384
#define ALPHA       0.5f
#define CHUNK       2048
#define BLOCK       256

// One block per class c:
//  - keep centers[c] in registers (float2 per thread, 256*2 = 512 floats)
//  - scan labels in chunks, collect matching row indices into LDS
//  - for each matching row: coalesced float2 load of features[row],
//    accumulate per-class feature sum in registers, block-reduce the
//    squared distance -> result[row] (each row matched by exactly one block)
//  - epilogue: new_centers[c] = centers[c] - ALPHA*(count*centers[c]-fsum)/(count+1)
__global__ __launch_bounds__(BLOCK, 4) void center_loss_kernel(
    const float* __restrict__ features,
    const float* __restrict__ centers,
    const int*   __restrict__ labels,
    float* __restrict__ result,        // [BATCH]
    float* __restrict__ new_centers)   // [NUM_CLASSES * FEAT_DIM]
{
    const int c   = blockIdx.x;
    const int tid = threadIdx.x;

    __shared__ int   match[CHUNK];
    __shared__ int   nmatch;
    __shared__ float wsum[BLOCK / 64];

    // center row in registers: 2 consecutive floats per thread
    const float2 ctr = ((const float2*)(centers + (size_t)c * FEAT_DIM))[tid];
    float2 fsum = make_float2(0.f, 0.f);
    int count = 0;

    for (int base = 0; base < BATCH; base += CHUNK) {
        if (tid == 0) nmatch = 0;
        __syncthreads();
        // scan this chunk of labels (L2-resident after first block touches it)
        for (int i = tid; i < CHUNK; i += BLOCK) {
            if (labels[base + i] == c) {
                int pos = atomicAdd(&nmatch, 1);
                match[pos] = base + i;
            }
        }
        __syncthreads();
        const int n = nmatch;   // uniform across block after barrier
        count += n;
        for (int r = 0; r < n; ++r) {
            const int row = match[r];
            const float2 f =
                ((const float2*)(features + (size_t)row * FEAT_DIM))[tid];
            fsum.x += f.x;
            fsum.y += f.y;
            const float dx = f.x - ctr.x;
            const float dy = f.y - ctr.y;
            float p = dx * dx + dy * dy;
            // wave-64 butterfly reduce
            #pragma unroll
            for (int off = 32; off > 0; off >>= 1)
                p += __shfl_down(p, off, 64);
            const int lane = tid & 63;
            const int wid  = tid >> 6;
            if (lane == 0) wsum[wid] = p;
            __syncthreads();
            if (tid == 0)
                result[row] = wsum[0] + wsum[1] + wsum[2] + wsum[3];
            __syncthreads();
        }
    }

    // epilogue: center update
    const float fc  = (float)count;
    const float inv = 1.0f / (fc + 1.0f);
    float2 out;
    out.x = ctr.x - ALPHA * (fc * ctr.x - fsum.x) * inv;
    out.y = ctr.y - ALPHA * (fc * ctr.y - fsum.y) * inv;
    ((float2*)(new_centers + (size_t)c * FEAT_DIM))[tid] = out;
}

extern "C" void kernel_launch(void* const* d_in, const int* in_sizes, int n_in,
                              void* d_out, int out_size, void* d_ws, size_t ws_size,
                              hipStream_t stream) {
    const float* features = (const float*)d_in[0];   // [BATCH, FEAT_DIM] f32
    const float* centers  = (const float*)d_in[1];   // [NUM_CLASSES, FEAT_DIM] f32
    const int*   labels   = (const int*)d_in[2];     // [BATCH] i32

    float* result      = (float*)d_out;              // [BATCH, 1]
    float* new_centers = (float*)d_out + BATCH;      // [NUM_CLASSES, FEAT_DIM]

    hipLaunchKernelGGL(center_loss_kernel,
                       dim3(NUM_CLASSES), dim3(BLOCK), 0, stream,
                       features, centers, labels, result, new_centers);
}

// Round 2
// 86.558 us; speedup vs baseline: 1.1627x; 1.1627x over previous
//
#include <hip/hip_runtime.h>

#define NUM_CLASSES 1024
#define FEAT_DIM    512
#define BATCH       16384
#define ALPHA       0.5f
#define CHUNK       2048
#define BLOCK       256

// One block per class c, 4 waves:
//  - each lane of each wave holds 8 columns of centers[c] (2x float4)
//  - label scan (int4) builds match list in LDS per 2048-row chunk
//  - rows are distributed to waves (r % 4): a wave loads the whole feature
//    row (8 floats/lane), accumulates per-wave fsum in registers, computes
//    the squared distance with a 6-step wave shuffle reduce -> result[row].
//    NO barriers inside the row loop; 4 rows in flight per block.
//  - epilogue: combine 4 waves' fsum via LDS, update new_centers[c].
__global__ __launch_bounds__(BLOCK, 4) void center_loss_kernel(
    const float* __restrict__ features,
    const float* __restrict__ centers,
    const int*   __restrict__ labels,
    float* __restrict__ result,        // [BATCH]
    float* __restrict__ new_centers)   // [NUM_CLASSES * FEAT_DIM]
{
    const int c    = blockIdx.x;
    const int tid  = threadIdx.x;
    const int lane = tid & 63;
    const int wid  = tid >> 6;

    __shared__ int   match[CHUNK];
    __shared__ int   nmatch;
    __shared__ float fsum_lds[4 * FEAT_DIM];   // 8 KB

    // center fragment: lane holds cols [lane*8, lane*8+8)
    const float4* cptr = (const float4*)(centers + (size_t)c * FEAT_DIM);
    const float4 ca = cptr[lane * 2 + 0];
    const float4 cb = cptr[lane * 2 + 1];

    float4 sa = make_float4(0.f, 0.f, 0.f, 0.f);
    float4 sb = make_float4(0.f, 0.f, 0.f, 0.f);
    int count = 0;

    for (int base = 0; base < BATCH; base += CHUNK) {
        __syncthreads();                 // prev chunk's match[] fully consumed
        if (tid == 0) nmatch = 0;
        __syncthreads();

        // vectorized label scan: 2048 labels as 512 int4, 2 per thread
        const int4* lab4 = (const int4*)(labels + base);
        #pragma unroll
        for (int i = tid; i < CHUNK / 4; i += BLOCK) {
            const int4 L = lab4[i];
            const int idx = base + i * 4;
            if (L.x == c) match[atomicAdd(&nmatch, 1)] = idx + 0;
            if (L.y == c) match[atomicAdd(&nmatch, 1)] = idx + 1;
            if (L.z == c) match[atomicAdd(&nmatch, 1)] = idx + 2;
            if (L.w == c) match[atomicAdd(&nmatch, 1)] = idx + 3;
        }
        __syncthreads();
        const int n = nmatch;            // uniform after barrier
        count += n;

        // rows distributed across the 4 waves; no barriers here
        for (int r = wid; r < n; r += 4) {
            const int row = match[r];
            const float4* fptr =
                (const float4*)(features + (size_t)row * FEAT_DIM);
            const float4 fa = fptr[lane * 2 + 0];
            const float4 fb = fptr[lane * 2 + 1];

            sa.x += fa.x; sa.y += fa.y; sa.z += fa.z; sa.w += fa.w;
            sb.x += fb.x; sb.y += fb.y; sb.z += fb.z; sb.w += fb.w;

            float dx, p;
            dx = fa.x - ca.x; p  = dx * dx;
            dx = fa.y - ca.y; p += dx * dx;
            dx = fa.z - ca.z; p += dx * dx;
            dx = fa.w - ca.w; p += dx * dx;
            dx = fb.x - cb.x; p += dx * dx;
            dx = fb.y - cb.y; p += dx * dx;
            dx = fb.z - cb.z; p += dx * dx;
            dx = fb.w - cb.w; p += dx * dx;

            #pragma unroll
            for (int m = 32; m > 0; m >>= 1)
                p += __shfl_xor(p, m, 64);
            if (lane == 0) result[row] = p;
        }
    }

    // ---- epilogue: combine the 4 waves' fsum, update centers ----
    __syncthreads();
    float4* dst = (float4*)&fsum_lds[wid * FEAT_DIM + lane * 8];
    dst[0] = sa;
    dst[1] = sb;
    __syncthreads();

    const int j0 = tid * 2;
    float s0 = 0.f, s1 = 0.f;
    #pragma unroll
    for (int w = 0; w < 4; ++w) {
        s0 += fsum_lds[w * FEAT_DIM + j0 + 0];
        s1 += fsum_lds[w * FEAT_DIM + j0 + 1];
    }

    const float2 ctr2 = ((const float2*)(centers + (size_t)c * FEAT_DIM))[tid];
    const float fc  = (float)count;
    const float inv = 1.0f / (fc + 1.0f);
    float2 out;
    out.x = ctr2.x - ALPHA * (fc * ctr2.x - s0) * inv;
    out.y = ctr2.y - ALPHA * (fc * ctr2.y - s1) * inv;
    ((float2*)(new_centers + (size_t)c * FEAT_DIM))[tid] = out;
}

extern "C" void kernel_launch(void* const* d_in, const int* in_sizes, int n_in,
                              void* d_out, int out_size, void* d_ws, size_t ws_size,
                              hipStream_t stream) {
    const float* features = (const float*)d_in[0];   // [BATCH, FEAT_DIM] f32
    const float* centers  = (const float*)d_in[1];   // [NUM_CLASSES, FEAT_DIM] f32
    const int*   labels   = (const int*)d_in[2];     // [BATCH] i32

    float* result      = (float*)d_out;              // [BATCH, 1]
    float* new_centers = (float*)d_out + BATCH;      // [NUM_CLASSES, FEAT_DIM]

    hipLaunchKernelGGL(center_loss_kernel,
                       dim3(NUM_CLASSES), dim3(BLOCK), 0, stream,
                       features, centers, labels, result, new_centers);
}